// Round 2
// baseline (1051.593 us; speedup 1.0000x reference)
//
#include <hip/hip_runtime.h>
#include <stdint.h>

#define B_ 8192
#define D_ 256
#define F_ 128
#define NTAB 500000

typedef unsigned short u16;
typedef unsigned int u32;
typedef __attribute__((ext_vector_type(8))) short bf16x8;
typedef __attribute__((ext_vector_type(4))) float f32x4;

__device__ __forceinline__ u16 f2bf(float v) {
  u32 u = __float_as_uint(v);
  u32 r = (u + 0x7fffu + ((u >> 16) & 1u)) >> 16;
  return (u16)r;
}
__device__ __forceinline__ float bf2f(u16 h) {
  return __uint_as_float(((u32)h) << 16);
}
__device__ __forceinline__ void f2hilo(float v, u16& h, u16& l) {
  h = f2bf(v);
  l = f2bf(v - bf2f(h));
}

// ---- distributed h_table copy: dst (out_table) starts at float index
// 2,097,153 (byte%16==4) -> build dst-aligned float4 from two aligned src
// float4s: dst4[524289+km] = {src[4km+3], src[4km+4], src[4km+5], src[4km+6]}.
// km domain: [0, 31,999,999). Head e=0..2 and tail e=127,999,999 patched in wconv.
__device__ __forceinline__ void copy_chunk(const float4* __restrict__ s,
                                           float4* __restrict__ d, long cofs,
                                           long ccnt, long bid, long nblk,
                                           int tid) {
  long i = cofs + bid * 256 + tid;
  long end = cofs + ccnt;
  long step = nblk * 256;
  for (; i < end; i += step) {
    float4 a = s[i];
    float4 b = s[i + 1];
    float4 o;
    o.x = a.w;
    o.y = b.x;
    o.z = b.y;
    o.w = b.z;
    d[524289 + i] = o;
  }
}

// ---------------- weight conversion (fp32 -> hi/lo bf16, with col padding) ----
struct WJobs {
  const float* src[10];
  u16* hi[10];
  u16* lo[10];
  int rows[10];
  int scols[10];
  int dcols[10];
};

__global__ __launch_bounds__(256) void wconv_kernel(WJobs jobs,
                                                    const float* __restrict__ htab,
                                                    float* __restrict__ otab) {
  int stride = gridDim.x * blockDim.x;
  int gid = blockIdx.x * blockDim.x + threadIdx.x;
  for (int j = 0; j < 10; ++j) {
    int dc = jobs.dcols[j];
    int sc = jobs.scols[j];
    int n = jobs.rows[j] * dc;
    const float* s = jobs.src[j];
    u16* ph = jobs.hi[j];
    u16* pl = jobs.lo[j];
    for (int i = gid; i < n; i += stride) {
      int r = i / dc;
      int c = i - r * dc;
      float v = (c < sc) ? s[r * sc + c] : 0.f;
      u16 h, l;
      f2hilo(v, h, l);
      ph[i] = h;
      pl[i] = l;
    }
  }
  if (gid == 0) {  // ragged head/tail of the table copy
    otab[0] = htab[0];
    otab[1] = htab[1];
    otab[2] = htab[2];
    otab[127999999] = htab[127999999];
  }
}

// ---------------- prep: X0 = concat(user_emb, feat) hi/lo; Hst = gather ----
__global__ __launch_bounds__(256) void prep_kernel(
    const float* __restrict__ user_emb, const float* __restrict__ feat,
    const float* __restrict__ h_table, const int* __restrict__ ids,
    u16* __restrict__ x0h, u16* __restrict__ x0l, float* __restrict__ hst,
    u16* __restrict__ hsh, u16* __restrict__ hsl,
    const float4* __restrict__ csrc, float4* __restrict__ cdst, long cofs,
    long ccnt) {
  int stride = gridDim.x * blockDim.x;
  int gid = blockIdx.x * blockDim.x + threadIdx.x;
  const int n1 = B_ * 384;
  for (int i = gid; i < n1; i += stride) {
    int b = i / 384;
    int c = i - b * 384;
    float v = (c < 256) ? user_emb[b * 256 + c] : feat[b * 128 + (c - 256)];
    u16 h, l;
    f2hilo(v, h, l);
    x0h[i] = h;
    x0l[i] = l;
  }
  const int n2 = B_ * 256;
  for (int i = gid; i < n2; i += stride) {
    int b = i >> 8;
    int c = i & 255;
    float v = h_table[(size_t)ids[b] * 256 + c];
    hst[i] = v;
    u16 h, l;
    f2hilo(v, h, l);
    hsh[i] = h;
    hsl[i] = l;
  }
  copy_chunk(csrc, cdst, cofs, ccnt, blockIdx.x, gridDim.x, threadIdx.x);
}

// ---------------- z_res = 1 - rowdot(item_emb, user_prior) ----
__global__ __launch_bounds__(256) void zres_kernel(
    const float* __restrict__ item_emb, const float* __restrict__ user_prior,
    float* __restrict__ zres, u16* __restrict__ xkh, u16* __restrict__ xkl) {
  int wave = threadIdx.x >> 6;
  int lane = threadIdx.x & 63;
  int b = blockIdx.x * 4 + wave;
  float s = 0.f;
#pragma unroll
  for (int i = 0; i < 4; ++i) {
    int d = lane + 64 * i;
    s += item_emb[(size_t)b * 256 + d] * user_prior[(size_t)b * 256 + d];
  }
#pragma unroll
  for (int m = 1; m < 64; m <<= 1) s += __shfl_xor(s, m);
  float z = 1.f - s;
  size_t rb = (size_t)b * 320;
  if (lane == 0) {
    zres[b] = z;
    u16 h, l;
    f2hilo(z, h, l);
    xkh[rb + 256] = h;
    xkl[rb + 256] = l;
  } else {
    int c = 256 + lane;  // 257..319 zero padding
    if (c < 320) {
      xkh[rb + c] = 0;
      xkl[rb + c] = 0;
    }
  }
}

// ---------------- GEMM: C[M,N] = A[M,K] @ W[N,K]^T + bias, hi/lo 3-MFMA ----
constexpr int EPI_HILO = 0;
constexpr int EPI_RELU_HILO = 1;
constexpr int EPI_F32 = 2;
constexpr int EPI_RES = 3;  // outf = acc+bias (epp); hi/lo(out - aux) -> Xkin

template <int EPI>
__global__ __launch_bounds__(256, 2) void gemm_hilo(
    const u16* __restrict__ Ahi, const u16* __restrict__ Alo,
    const u16* __restrict__ Bhi, const u16* __restrict__ Blo,
    const float* __restrict__ bias, int K, float* __restrict__ outf, int ldf,
    u16* __restrict__ outh, u16* __restrict__ outl, int ldo,
    const float* __restrict__ aux, const float4* __restrict__ csrc,
    float4* __restrict__ cdst, long cofs, long ccnt, int nyg) {
  __shared__ u16 smem[4 * 4096];  // Ahi | Alo | Bhi | Blo tiles, 64x64 bf16
  if ((int)blockIdx.y >= nyg) {   // copy-role block (overlaps table copy)
    long nblk = (long)(gridDim.y - nyg) * gridDim.x;
    long bid = (long)(blockIdx.y - nyg) * gridDim.x + blockIdx.x;
    copy_chunk(csrc, cdst, cofs, ccnt, bid, nblk, threadIdx.x);
    return;
  }
  const int tid = threadIdx.x;
  const int wave = tid >> 6;
  const int lane = tid & 63;
  const int rowBase = blockIdx.x * 64;
  const int colBase = blockIdx.y * 64;
  const int wm = wave >> 1;
  const int wn = wave & 1;

  const u16* srcs[4] = {Ahi + (size_t)rowBase * K, Alo + (size_t)rowBase * K,
                        Bhi + (size_t)colBase * K, Blo + (size_t)colBase * K};
  const u16* src = srcs[wave];
  u16* ldsbase = &smem[wave * 4096];

  const int r8 = lane >> 3;           // row within 8-row stripe
  const int chunk = (lane & 7) ^ r8;  // pre-swizzled global 16B-chunk index
  const int c16 = lane & 15;
  const int g = lane >> 4;

  f32x4 acc[2][2];
#pragma unroll
  for (int i = 0; i < 2; ++i)
#pragma unroll
    for (int j = 0; j < 2; ++j) acc[i][j] = (f32x4){0.f, 0.f, 0.f, 0.f};

  for (int k0 = 0; k0 < K; k0 += 64) {
#pragma unroll
    for (int j = 0; j < 8; ++j) {
      int row = (j << 3) + r8;
      const u16* gp = src + (size_t)row * K + k0 + chunk * 8;
      __builtin_amdgcn_global_load_lds(
          (const __attribute__((address_space(1))) void*)gp,
          (__attribute__((address_space(3))) void*)(ldsbase + j * 512), 16, 0,
          0);
    }
    __syncthreads();
#pragma unroll
    for (int s = 0; s < 2; ++s) {
      bf16x8 ah[2], al[2], bh[2], bl[2];
#pragma unroll
      for (int fm = 0; fm < 2; ++fm) {
        int r = wm * 32 + fm * 16 + c16;
        int off = r * 64 + (((s * 4 + g) ^ (r & 7)) << 3);
        ah[fm] = *(const bf16x8*)&smem[0 * 4096 + off];
        al[fm] = *(const bf16x8*)&smem[1 * 4096 + off];
      }
#pragma unroll
      for (int fn = 0; fn < 2; ++fn) {
        int c = wn * 32 + fn * 16 + c16;
        int off = c * 64 + (((s * 4 + g) ^ (c & 7)) << 3);
        bh[fn] = *(const bf16x8*)&smem[2 * 4096 + off];
        bl[fn] = *(const bf16x8*)&smem[3 * 4096 + off];
      }
#pragma unroll
      for (int fm = 0; fm < 2; ++fm)
#pragma unroll
        for (int fn = 0; fn < 2; ++fn) {
          acc[fm][fn] = __builtin_amdgcn_mfma_f32_16x16x32_bf16(
              ah[fm], bh[fn], acc[fm][fn], 0, 0, 0);
          acc[fm][fn] = __builtin_amdgcn_mfma_f32_16x16x32_bf16(
              ah[fm], bl[fn], acc[fm][fn], 0, 0, 0);
          acc[fm][fn] = __builtin_amdgcn_mfma_f32_16x16x32_bf16(
              al[fm], bh[fn], acc[fm][fn], 0, 0, 0);
        }
    }
    __syncthreads();
  }

  // epilogue: C frag layout col = lane&15, row = (lane>>4)*4 + reg (m89)
#pragma unroll
  for (int fm = 0; fm < 2; ++fm)
#pragma unroll
    for (int fn = 0; fn < 2; ++fn) {
      int colg = colBase + wn * 32 + fn * 16 + c16;
      float bv = bias[colg];
#pragma unroll
      for (int j = 0; j < 4; ++j) {
        int rowg = rowBase + wm * 32 + fm * 16 + g * 4 + j;
        float v = acc[fm][fn][j] + bv;
        if constexpr (EPI == EPI_RELU_HILO) {
          v = fmaxf(v, 0.f);
          u16 h, l;
          f2hilo(v, h, l);
          outh[(size_t)rowg * ldo + colg] = h;
          outl[(size_t)rowg * ldo + colg] = l;
        } else if constexpr (EPI == EPI_HILO) {
          u16 h, l;
          f2hilo(v, h, l);
          outh[(size_t)rowg * ldo + colg] = h;
          outl[(size_t)rowg * ldo + colg] = l;
        } else if constexpr (EPI == EPI_F32) {
          outf[(size_t)rowg * ldf + colg] = v;
        } else {  // EPI_RES
          outf[(size_t)rowg * ldf + colg] = v;
          float r2 = v - aux[(size_t)rowg * 256 + colg];
          u16 h, l;
          f2hilo(r2, h, l);
          outh[(size_t)rowg * ldo + colg] = h;
          outl[(size_t)rowg * ldo + colg] = l;
        }
      }
    }
}

// ---------------- GRU gates (h_state -> workspace; scatter deferred) ----
__global__ __launch_bounds__(256) void gru_kernel(
    const float* __restrict__ gi, const float* __restrict__ gh,
    const float* __restrict__ hst, u16* __restrict__ hnh,
    u16* __restrict__ hnl, float* __restrict__ hnewf,
    const float4* __restrict__ csrc, float4* __restrict__ cdst, long cofs,
    long ccnt) {
  int stride = gridDim.x * blockDim.x;
  for (int i = blockIdx.x * blockDim.x + threadIdx.x; i < B_ * 256;
       i += stride) {
    size_t base = (size_t)(i >> 8) * 768;
    int d = i & 255;
    float ir = gi[base + d], iz = gi[base + 256 + d], inn = gi[base + 512 + d];
    float hr = gh[base + d], hz = gh[base + 256 + d], hn = gh[base + 512 + d];
    float r = 1.f / (1.f + __expf(-(ir + hr)));
    float z = 1.f / (1.f + __expf(-(iz + hz)));
    float n = tanhf(inn + r * hn);
    float h = (1.f - z) * n + z * hst[i];
    u16 hh, ll;
    f2hilo(h, hh, ll);
    hnh[i] = hh;
    hnl[i] = ll;
    hnewf[i] = h;
  }
  copy_chunk(csrc, cdst, cofs, ccnt, blockIdx.x, gridDim.x, threadIdx.x);
}

// ---------------- final: emb_post, normalize, residual, deferred scatter ----
__global__ __launch_bounds__(256) void fin_kernel(
    const float* __restrict__ Kmat, const float* __restrict__ user_prior,
    const float* __restrict__ epp, const float* __restrict__ zres,
    const float* __restrict__ hnewf, const int* __restrict__ ids,
    float* __restrict__ out, float* __restrict__ otab,
    float* __restrict__ partial) {
  __shared__ float sh[4];
  int wave = threadIdx.x >> 6;
  int lane = threadIdx.x & 63;
  int b = blockIdx.x * 4 + wave;
  float z = zres[b];
  size_t rb = (size_t)b * 256;
  size_t orow = (size_t)ids[b] * 256;
  float post[4];
  float sres = 0.f, snrm = 0.f;
#pragma unroll
  for (int i = 0; i < 4; ++i) {
    int d = lane + 64 * i;
    float p = user_prior[rb + d] + Kmat[rb + d] * z;
    post[i] = p;
    float e = epp[rb + d] - p;
    sres += e * e;
    snrm += p * p;
    otab[orow + d] = hnewf[rb + d];  // scatter h_new (after all copy chunks)
  }
#pragma unroll
  for (int m = 1; m < 64; m <<= 1) {
    sres += __shfl_xor(sres, m);
    snrm += __shfl_xor(snrm, m);
  }
  float denom = fmaxf(sqrtf(snrm), 1e-12f);
#pragma unroll
  for (int i = 0; i < 4; ++i) out[rb + lane + 64 * i] = post[i] / denom;
  if (lane == 0) sh[wave] = sres;
  __syncthreads();
  if (threadIdx.x == 0) partial[blockIdx.x] = sh[0] + sh[1] + sh[2] + sh[3];
}

__global__ __launch_bounds__(256) void regu_kernel(
    const float* __restrict__ partial, float* __restrict__ out_scalar) {
  __shared__ float sh[4];
  float s = 0.f;
  for (int i = threadIdx.x; i < 2048; i += 256) s += partial[i];
#pragma unroll
  for (int m = 1; m < 64; m <<= 1) s += __shfl_xor(s, m);
  int wave = threadIdx.x >> 6;
  int lane = threadIdx.x & 63;
  if (lane == 0) sh[wave] = s;
  __syncthreads();
  if (threadIdx.x == 0) out_scalar[0] = sqrtf(sh[0] + sh[1] + sh[2] + sh[3]);
}

// =======================================================================
extern "C" void kernel_launch(void* const* d_in, const int* in_sizes, int n_in,
                              void* d_out, int out_size, void* d_ws,
                              size_t ws_size, hipStream_t stream) {
  const int* ids = (const int*)d_in[0];
  const float* user_prior = (const float*)d_in[1];
  const float* user_emb = (const float*)d_in[2];
  const float* item_emb = (const float*)d_in[3];
  const float* feat = (const float*)d_in[4];
  const float* h_table = (const float*)d_in[5];
  const float* tran_W0 = (const float*)d_in[6];
  const float* tran_b0 = (const float*)d_in[7];
  const float* tran_W1 = (const float*)d_in[8];
  const float* tran_b1 = (const float*)d_in[9];
  const float* pred_W0 = (const float*)d_in[10];
  const float* pred_b0 = (const float*)d_in[11];
  const float* pred_W1 = (const float*)d_in[12];
  const float* pred_b1 = (const float*)d_in[13];
  const float* kin_W0 = (const float*)d_in[14];
  const float* kin_b0 = (const float*)d_in[15];
  const float* kin_W1 = (const float*)d_in[16];
  const float* kin_b1 = (const float*)d_in[17];
  const float* gru_Wih = (const float*)d_in[18];
  const float* gru_Whh = (const float*)d_in[19];
  const float* gru_bih = (const float*)d_in[20];
  const float* gru_bhh = (const float*)d_in[21];
  const float* kout_W0 = (const float*)d_in[22];
  const float* kout_b0 = (const float*)d_in[23];
  const float* kout_W1 = (const float*)d_in[24];
  const float* kout_b1 = (const float*)d_in[25];

  float* out_mat = (float*)d_out;                 // [B, D]
  float* out_scalar = out_mat + (size_t)B_ * D_;  // [1]
  float* out_table = out_scalar + 1;              // [NTAB, D]
  const float4* csrc = (const float4*)h_table;
  float4* cdst = (float4*)d_out;  // indexed 524289+km (16B-aligned from base)

  // ---- workspace layout ----
  char* p = (char*)d_ws;
  auto alloc = [&](size_t bytes) -> char* {
    char* r = p;
    p += (bytes + 255) & ~(size_t)255;
    return r;
  };

  static const int wrows[10] = {256, 256, 256, 256, 256,
                                256, 768, 768, 256, 256};
  static const int wscols[10] = {384, 256, 256, 256, 257,
                                 256, 256, 256, 256, 256};
  static const int wdcols[10] = {384, 256, 256, 256, 320,
                                 256, 256, 256, 256, 256};
  const float* wsrc[10] = {tran_W0, tran_W1, pred_W0, pred_W1, kin_W0,
                           kin_W1,  gru_Wih, gru_Whh, kout_W0, kout_W1};
  u16* wh[10];
  u16* wl[10];
  for (int j = 0; j < 10; ++j) {
    size_t n = (size_t)wrows[j] * wdcols[j];
    wh[j] = (u16*)alloc(n * 2);
    wl[j] = (u16*)alloc(n * 2);
  }

  u16* x0h = (u16*)alloc((size_t)B_ * 384 * 2);  // pool P1: X0 -> H2 -> H4
  u16* x0l = (u16*)alloc((size_t)B_ * 384 * 2);
  u16* p2h = (u16*)alloc((size_t)B_ * 256 * 2);  // pool P2: H1 -> H3 -> Hnew
  u16* p2l = (u16*)alloc((size_t)B_ * 256 * 2);
  u16* p3h = (u16*)alloc((size_t)B_ * 256 * 2);  // pool P3: emb -> k_in
  u16* p3l = (u16*)alloc((size_t)B_ * 256 * 2);
  u16* xkh = (u16*)alloc((size_t)B_ * 320 * 2);  // Xkin [B,320]
  u16* xkl = (u16*)alloc((size_t)B_ * 320 * 2);
  float* hst = (float*)alloc((size_t)B_ * 256 * 4);
  u16* hsh = (u16*)alloc((size_t)B_ * 256 * 2);
  u16* hsl = (u16*)alloc((size_t)B_ * 256 * 2);
  float* epp = (float*)alloc((size_t)B_ * 256 * 4);
  float* gi = (float*)alloc((size_t)B_ * 768 * 4);  // also reused as Kmat
  float* gh = (float*)alloc((size_t)B_ * 768 * 4);
  float* hnewf = (float*)alloc((size_t)B_ * 256 * 4);
  float* zres = (float*)alloc((size_t)B_ * 4);
  float* partial = (float*)alloc(2048 * 4);
  (void)ws_size;
  (void)in_sizes;
  (void)n_in;
  (void)out_size;

  WJobs jobs;
  for (int j = 0; j < 10; ++j) {
    jobs.src[j] = wsrc[j];
    jobs.hi[j] = wh[j];
    jobs.lo[j] = wl[j];
    jobs.rows[j] = wrows[j];
    jobs.scols[j] = wscols[j];
    jobs.dcols[j] = wdcols[j];
  }

  // ---- copy-chunk distribution (km units; see copy_chunk) ----
  // order: prep,G1,G2,G3,G4,G5,G6,G7,G8,gru,G9,G10
  const long KMT = 31999999;
  const int wgt[12] = {2, 6, 4, 4, 4, 5, 4, 12, 12, 3, 4, 4};  // sum 64
  long ofs[12], cnt[12], accum = 0;
  for (int i = 0; i < 12; ++i) {
    cnt[i] = KMT * (long)wgt[i] / 64;
    ofs[i] = accum;
    accum += cnt[i];
  }
  cnt[11] += KMT - accum;  // remainder to G10

  dim3 blk(256);
  const int CY = 4;  // copy-role grid rows per GEMM launch
  dim3 g256(128, 4 + CY);
  dim3 g768(128, 12 + CY);

  wconv_kernel<<<1024, blk, 0, stream>>>(jobs, h_table, out_table);
  prep_kernel<<<2048, blk, 0, stream>>>(user_emb, feat, h_table, ids, x0h, x0l,
                                        hst, hsh, hsl, csrc, cdst, ofs[0],
                                        cnt[0]);
  zres_kernel<<<2048, blk, 0, stream>>>(item_emb, user_prior, zres, xkh, xkl);

  // G1: H1 = relu(X0 @ tranW0^T + b0)
  gemm_hilo<EPI_RELU_HILO><<<g256, blk, 0, stream>>>(
      x0h, x0l, wh[0], wl[0], tran_b0, 384, nullptr, 0, p2h, p2l, 256, nullptr,
      csrc, cdst, ofs[1], cnt[1], 4);
  // G2: emb = H1 @ tranW1^T + b1
  gemm_hilo<EPI_HILO><<<g256, blk, 0, stream>>>(
      p2h, p2l, wh[1], wl[1], tran_b1, 256, nullptr, 0, p3h, p3l, 256, nullptr,
      csrc, cdst, ofs[2], cnt[2], 4);
  // G3: H2 = relu(emb @ predW0^T + b0)
  gemm_hilo<EPI_RELU_HILO><<<g256, blk, 0, stream>>>(
      p3h, p3l, wh[2], wl[2], pred_b0, 256, nullptr, 0, x0h, x0l, 256, nullptr,
      csrc, cdst, ofs[3], cnt[3], 4);
  // G4: epp = H2 @ predW1^T + b1 ; Xkin[:,0:256] = hi/lo(epp - user_prior)
  gemm_hilo<EPI_RES><<<g256, blk, 0, stream>>>(
      x0h, x0l, wh[3], wl[3], pred_b1, 256, epp, 256, xkh, xkl, 320, user_prior,
      csrc, cdst, ofs[4], cnt[4], 4);
  // G5: H3 = relu(Xkin @ kinW0p^T + b0)   (K = 320, zero-padded)
  gemm_hilo<EPI_RELU_HILO><<<g256, blk, 0, stream>>>(
      xkh, xkl, wh[4], wl[4], kin_b0, 320, nullptr, 0, p2h, p2l, 256, nullptr,
      csrc, cdst, ofs[5], cnt[5], 4);
  // G6: k_in = H3 @ kinW1^T + b1
  gemm_hilo<EPI_HILO><<<g256, blk, 0, stream>>>(
      p2h, p2l, wh[5], wl[5], kin_b1, 256, nullptr, 0, p3h, p3l, 256, nullptr,
      csrc, cdst, ofs[6], cnt[6], 4);
  // G7: gi = k_in @ Wih^T + bih  (N = 768)
  gemm_hilo<EPI_F32><<<g768, blk, 0, stream>>>(
      p3h, p3l, wh[6], wl[6], gru_bih, 256, gi, 768, nullptr, nullptr, 0,
      nullptr, csrc, cdst, ofs[7], cnt[7], 12);
  // G8: gh = Hst @ Whh^T + bhh  (N = 768)
  gemm_hilo<EPI_F32><<<g768, blk, 0, stream>>>(
      hsh, hsl, wh[7], wl[7], gru_bhh, 256, gh, 768, nullptr, nullptr, 0,
      nullptr, csrc, cdst, ofs[8], cnt[8], 12);
  // GRU gates -> hnewf (scatter deferred to fin)
  gru_kernel<<<2048, blk, 0, stream>>>(gi, gh, hst, p2h, p2l, hnewf, csrc, cdst,
                                       ofs[9], cnt[9]);
  // G9: H4 = relu(Hnew @ koutW0^T + b0)
  gemm_hilo<EPI_RELU_HILO><<<g256, blk, 0, stream>>>(
      p2h, p2l, wh[8], wl[8], kout_b0, 256, nullptr, 0, x0h, x0l, 256, nullptr,
      csrc, cdst, ofs[10], cnt[10], 4);
  // G10: Kmat = H4 @ koutW1^T + b1  (Kmat aliases gi)
  gemm_hilo<EPI_F32><<<g256, blk, 0, stream>>>(
      x0h, x0l, wh[9], wl[9], kout_b1, 256, gi, 256, nullptr, nullptr, 0,
      nullptr, csrc, cdst, ofs[11], cnt[11], 4);
  // final: emb_post, normalize, residual partials, h_new scatter (post-copy)
  fin_kernel<<<2048, blk, 0, stream>>>(gi, user_prior, epp, zres, hnewf, ids,
                                       out_mat, out_table, partial);
  regu_kernel<<<1, blk, 0, stream>>>(partial, out_scalar);
}